// Round 2
// baseline (5232.911 us; speedup 1.0000x reference)
//
#include <hip/hip_runtime.h>
#include <hip/hip_bf16.h>
#include <math.h>

#define C_   1024
#define P_   2304      // 48*48
#define S4   331776    // 24^4

typedef __attribute__((ext_vector_type(8))) short short8;
typedef __attribute__((ext_vector_type(4))) float f32x4;

__device__ inline unsigned short f2bf(float v) {
  unsigned u = __builtin_bit_cast(unsigned, v);
  u += 0x7fffu + ((u >> 16) & 1u);          // RNE
  return (unsigned short)(u >> 16);
}
__device__ inline float bf2f(unsigned short h) {
  unsigned u = ((unsigned)h) << 16;
  return __builtin_bit_cast(float, u);
}

// ---------------- K1: transpose + bf16 hi/lo split + sumsq partials --------
// grid (16 ctiles, 36 ptiles, 2 feats), block 256. Per batch b.
// Out: T*[p][c] (bf16 bits), part[feat][ctile][p].
__global__ __launch_bounds__(256) void k_prep(
    const float* __restrict__ fA, const float* __restrict__ fB, int b,
    unsigned short* __restrict__ TAhi, unsigned short* __restrict__ TAlo,
    unsigned short* __restrict__ TBhi, unsigned short* __restrict__ TBlo,
    float* __restrict__ part) {
  __shared__ float ld[64 * 65];
  __shared__ float pslds[512];
  const int c0 = blockIdx.x * 64, p0 = blockIdx.y * 64, f = blockIdx.z;
  const float* src = (f ? fB : fA) + (size_t)b * C_ * P_;
  unsigned short* Thi = f ? TBhi : TAhi;
  unsigned short* Tlo = f ? TBlo : TAlo;
  const int t = threadIdx.x;
#pragma unroll
  for (int e = 0; e < 4; ++e) {
    int cid = t + e * 256;                  // 0..1023
    int r = cid >> 4, ch = cid & 15;
    float4 v = *(const float4*)&src[(size_t)(c0 + r) * P_ + p0 + ch * 4];
    ld[r * 65 + ch * 4 + 0] = v.x;
    ld[r * 65 + ch * 4 + 1] = v.y;
    ld[r * 65 + ch * 4 + 2] = v.z;
    ld[r * 65 + ch * 4 + 3] = v.w;
  }
  __syncthreads();
#pragma unroll
  for (int e = 0; e < 2; ++e) {
    int ocid = t + e * 256;                 // 0..511
    int pl = ocid >> 3, c8 = ocid & 7;
    unsigned short hi[8], lo[8];
    float sq = 0.f;
#pragma unroll
    for (int s = 0; s < 8; ++s) {
      float v = ld[(c8 * 8 + s) * 65 + pl];
      unsigned short h = f2bf(v);
      float rem = v - bf2f(h);
      hi[s] = h; lo[s] = f2bf(rem);
      sq = fmaf(v, v, sq);
    }
    size_t go = (size_t)(p0 + pl) * C_ + c0 + c8 * 8;
    *(uint4*)&Thi[go] = *(uint4*)hi;
    *(uint4*)&Tlo[go] = *(uint4*)lo;
    pslds[ocid] = sq;
  }
  __syncthreads();
  if (t < 64) {
    float s = 0.f;
#pragma unroll
    for (int c8 = 0; c8 < 8; ++c8) s += pslds[t * 8 + c8];
    part[(size_t)(f * 16 + blockIdx.x) * P_ + p0 + t] = s;
  }
}

// ---------------- K2: finalize inverse norms (per batch) -------------------
__global__ void k_invnorm(const float* __restrict__ part, float* __restrict__ inv, int b) {
  int p = blockIdx.x * 256 + threadIdx.x;
  int f = blockIdx.y;
  float s = 1e-6f;
  for (int ct = 0; ct < 16; ++ct) s += part[(size_t)(f * 16 + ct) * P_ + p];
  inv[(size_t)(f * 8 + b) * P_ + p] = 1.0f / sqrtf(s);
}

// ---------------- K3: bf16x3 MFMA correlation + relu/norm/4D-maxpool -------
// 96x96 tile, 4 waves of 48x48 (3x3 of 16x16x32), 3 passes hh+hl+lh.
__global__ __launch_bounds__(256) void k_corr_mfma(
    const unsigned short* __restrict__ TAhi, const unsigned short* __restrict__ TAlo,
    const unsigned short* __restrict__ TBhi, const unsigned short* __restrict__ TBlo,
    const float* __restrict__ invn, int b, float* __restrict__ out) {
  __shared__ __align__(16) char lds_raw[37248];
  unsigned short* stage = (unsigned short*)lds_raw;   // 4 arrays of 96x40
  float* epi = (float*)lds_raw;                       // 96x97 f32 overlay

  const int ti = blockIdx.x / 24, tj = blockIdx.x % 24;
  const int p0 = ti * 96, q0 = tj * 96;
  const int t = threadIdx.x;
  const int lane = t & 63, w = t >> 6;
  const int wr = w >> 1, wc = w & 1;
  const int m15 = lane & 15, q4 = lane >> 4;
  const int koff = q4 * 8;

  f32x4 acc[3][3];
#pragma unroll
  for (int a = 0; a < 3; ++a)
#pragma unroll
    for (int c = 0; c < 3; ++c) acc[a][c] = (f32x4){0.f, 0.f, 0.f, 0.f};

  // per-thread staging chunk descriptors (6 chunks of 16B)
  uint4 pre[6];
  const unsigned short* gsrc[6];
  int ldsoff[6];
#pragma unroll
  for (int e = 0; e < 6; ++e) {
    int cid = t + e * 256;                 // 0..1535
    int arr = cid / 384, wi = cid % 384;
    int rr = wi >> 2, kc = wi & 3;
    const unsigned short* base = (arr == 0) ? TAhi : (arr == 1) ? TAlo
                               : (arr == 2) ? TBhi : TBlo;
    int pb = (arr < 2) ? p0 : q0;
    gsrc[e] = base + (size_t)(pb + rr) * C_ + kc * 8;
    ldsoff[e] = arr * 3840 + rr * 40 + kc * 8;
  }
#pragma unroll
  for (int e = 0; e < 6; ++e) pre[e] = *(const uint4*)(gsrc[e]);   // kt=0

  for (int kt = 0; kt < C_; kt += 32) {
    __syncthreads();
#pragma unroll
    for (int e = 0; e < 6; ++e) *(uint4*)&stage[ldsoff[e]] = pre[e];
    __syncthreads();
    if (kt + 32 < C_) {
#pragma unroll
      for (int e = 0; e < 6; ++e) pre[e] = *(const uint4*)(gsrc[e] + kt + 32);
    }
    const unsigned short* Ah = stage;
    const unsigned short* Al = stage + 3840;
    const unsigned short* Bh = stage + 7680;
    const unsigned short* Bl = stage + 11520;
    short8 ah[3], al[3], bh[3], bl[3];
#pragma unroll
    for (int a = 0; a < 3; ++a) {
      int row = wr * 48 + a * 16 + m15;
      ah[a] = *(const short8*)&Ah[row * 40 + koff];
      al[a] = *(const short8*)&Al[row * 40 + koff];
    }
#pragma unroll
    for (int c = 0; c < 3; ++c) {
      int row = wc * 48 + c * 16 + m15;
      bh[c] = *(const short8*)&Bh[row * 40 + koff];
      bl[c] = *(const short8*)&Bl[row * 40 + koff];
    }
#pragma unroll
    for (int a = 0; a < 3; ++a)
#pragma unroll
      for (int c = 0; c < 3; ++c)
        acc[a][c] = __builtin_amdgcn_mfma_f32_16x16x32_bf16(ah[a], bh[c], acc[a][c], 0, 0, 0);
#pragma unroll
    for (int a = 0; a < 3; ++a)
#pragma unroll
      for (int c = 0; c < 3; ++c)
        acc[a][c] = __builtin_amdgcn_mfma_f32_16x16x32_bf16(ah[a], bl[c], acc[a][c], 0, 0, 0);
#pragma unroll
    for (int a = 0; a < 3; ++a)
#pragma unroll
      for (int c = 0; c < 3; ++c)
        acc[a][c] = __builtin_amdgcn_mfma_f32_16x16x32_bf16(al[a], bh[c], acc[a][c], 0, 0, 0);
  }
  __syncthreads();   // all frag reads done before overwriting stage with epi

  const float* invA = invn + (size_t)b * P_;
  const float* invB = invn + (size_t)(8 + b) * P_;
  float ib[3];
#pragma unroll
  for (int c = 0; c < 3; ++c) ib[c] = invB[q0 + wc * 48 + c * 16 + m15];
#pragma unroll
  for (int a = 0; a < 3; ++a) {
#pragma unroll
    for (int reg = 0; reg < 4; ++reg) {
      int pl = wr * 48 + a * 16 + q4 * 4 + reg;
      float ia = invA[p0 + pl];
#pragma unroll
      for (int c = 0; c < 3; ++c) {
        int ql = wc * 48 + c * 16 + m15;
        epi[pl * 97 + ql] = acc[a][c][reg] * ia * ib[c];
      }
    }
  }
  __syncthreads();

  // 2x2x2x2 max pool, then relu + x/sqrt(x^2+eps) (monotone -> after max)
  for (int idx = t; idx < 576; idx += 256) {
    int j = idx / 24, l = idx % 24;
    float m = -1e30f;
#pragma unroll
    for (int dh = 0; dh < 2; ++dh)
#pragma unroll
      for (int dw = 0; dw < 2; ++dw) {
        int row = dh * 48 + 2 * j + dw;
#pragma unroll
        for (int d2 = 0; d2 < 2; ++d2)
#pragma unroll
          for (int dw2 = 0; dw2 < 2; ++dw2)
            m = fmaxf(m, epi[row * 97 + d2 * 48 + 2 * l + dw2]);
      }
    float r = fmaxf(m, 0.f);
    float v = r / sqrtf(r * r + 1e-6f);
    out[(size_t)(ti * 24 + j) * 576 + tj * 24 + l] = v;
  }
}

// ---------------- K4a: row max (over kl, per ij) ---------------------------
__global__ void k_rowmax(const float* __restrict__ x, float* __restrict__ amax) {
  int row = blockIdx.x;                       // b*576 + ij
  const float* r = x + (size_t)row * 576;
  float m = -1e30f;
  for (int e = threadIdx.x; e < 576; e += 64) m = fmaxf(m, r[e]);
  for (int off = 32; off > 0; off >>= 1) m = fmaxf(m, __shfl_down(m, off, 64));
  if (threadIdx.x == 0) amax[row] = m;
}

// ---------------- K4b: col max (over ij, per kl) — parallelized ------------
__global__ void k_colmax(const float* __restrict__ x, float* __restrict__ bmax) {
  __shared__ float pl[4][64];
  int b = blockIdx.x, klc = blockIdx.y * 64;
  int t = threadIdx.x;
  int kl = klc + (t & 63), seg = t >> 6;
  const float* xb = x + (size_t)b * S4;
  float m = -1e30f;
  for (int ij = seg * 144; ij < (seg + 1) * 144; ++ij)
    m = fmaxf(m, xb[(size_t)ij * 576 + kl]);
  pl[seg][t & 63] = m;
  __syncthreads();
  if (t < 64) {
    float r = fmaxf(fmaxf(pl[0][t], pl[1][t]), fmaxf(pl[2][t], pl[3][t]));
    bmax[b * 576 + klc + t] = r;
  }
}

// ---------------- K5: mutual matching elementwise --------------------------
__global__ void k_mm_apply(const float* __restrict__ x,
                           const float* __restrict__ amax,
                           const float* __restrict__ bmax,
                           float* __restrict__ y) {
  int i = blockIdx.x * 256 + threadIdx.x;     // < 8*S4
  int b = i / S4, r = i % S4;
  int ij = r / 576, kl = r % 576;
  float c = x[i];
  y[i] = c * (c / (amax[b * 576 + ij] + 1e-5f)) * (c / (bmax[b * 576 + kl] + 1e-5f));
}

// ---------------- K6: direct 4D conv, block-staged halo --------------------
// block per (i,j), 576 threads over (k,l); per-ci stage 3x3x26x26 zero-padded
// halo block (2 syncs/ci); 81 taps x COUT FMAs, wave-uniform weight indices.
template <int CIN, int COUT>
__global__ __launch_bounds__(576) void k_conv4d(
    const float* __restrict__ x, const float* __restrict__ w,
    const float* __restrict__ bias, float* __restrict__ y) {
  __shared__ float tile[9 * 26 * 26];
  const int ij = blockIdx.x;
  const int i = ij / 24, j = ij % 24;
  const int t = threadIdx.x;
  const int k = t / 24, l = t % 24;
  float acc[COUT];
#pragma unroll
  for (int co = 0; co < COUT; ++co) acc[co] = 0.f;

  for (int ci = 0; ci < CIN; ++ci) {
    __syncthreads();
    for (int e = t; e < 9 * 676; e += 576) {
      int pln = e / 676, rem = e % 676;
      int di = pln / 3, dj = pln % 3;
      int kk = rem / 26 - 1, ll = rem % 26 - 1;
      int ii = i + di - 1, jj = j + dj - 1;
      float v = 0.f;
      if (ii >= 0 && ii < 24 && jj >= 0 && jj < 24 &&
          kk >= 0 && kk < 24 && ll >= 0 && ll < 24)
        v = x[((size_t)(ci * 24 + ii) * 24 + jj) * 576 + kk * 24 + ll];
      tile[e] = v;
    }
    __syncthreads();
#pragma unroll
    for (int di = 0; di < 3; ++di)
#pragma unroll
      for (int dj = 0; dj < 3; ++dj) {
        const float* pl = &tile[(di * 3 + dj) * 676];
        float tap[9];
#pragma unroll
        for (int dk = 0; dk < 3; ++dk)
#pragma unroll
          for (int dl = 0; dl < 3; ++dl)
            tap[dk * 3 + dl] = pl[(k + dk) * 26 + (l + dl)];
        const float* wp = w + ci * 81 + (di * 3 + dj) * 9;
#pragma unroll
        for (int co = 0; co < COUT; ++co)
#pragma unroll
          for (int tt = 0; tt < 9; ++tt)
            acc[co] = fmaf(tap[tt], wp[(size_t)co * CIN * 81 + tt], acc[co]);
      }
  }
#pragma unroll
  for (int co = 0; co < COUT; ++co) {
    float v = fmaxf(acc[co] + bias[co], 0.f);
    y[(size_t)co * S4 + (size_t)ij * 576 + t] = v;
  }
}

// ---------------------------------------------------------------------------
extern "C" void kernel_launch(void* const* d_in, const int* in_sizes, int n_in,
                              void* d_out, int out_size, void* d_ws, size_t ws_size,
                              hipStream_t stream) {
  const float* fA = (const float*)d_in[0];
  const float* fB = (const float*)d_in[1];
  const float* w1 = (const float*)d_in[2];
  const float* b1 = (const float*)d_in[3];
  const float* w2 = (const float*)d_in[4];
  const float* b2 = (const float*)d_in[5];
  const float* w3 = (const float*)d_in[6];
  const float* b3 = (const float*)d_in[7];
  float* out = (float*)d_out;

  float* ws = (float*)d_ws;
  size_t off = 0;
  auto alloc = [&](size_t n) {
    float* p = ws + off;
    off += (n + 63) & ~(size_t)63;
    return p;
  };
  float* pooled = alloc((size_t)8 * S4);        // 10.6 MB
  float* C3     = alloc((size_t)8 * S4);        // 10.6 MB
  float* part   = alloc((size_t)2 * 16 * P_);
  float* invn   = alloc((size_t)16 * P_);
  float* amax1  = alloc(8 * 576);
  float* bmax1  = alloc(8 * 576);
  float* amax2  = alloc(8 * 576);
  float* bmax2  = alloc(8 * 576);
  float* X      = alloc((size_t)20 * S4);       // 26.5 MB: T (18.9) aliases C1+C2
  float* C1 = X;
  float* C2 = X + (size_t)10 * S4;
  unsigned short* TAhi = (unsigned short*)X;    // each 2304*1024 ushorts
  unsigned short* TAlo = TAhi + (size_t)P_ * C_;
  unsigned short* TBhi = TAlo + (size_t)P_ * C_;
  unsigned short* TBlo = TBhi + (size_t)P_ * C_;
  (void)in_sizes; (void)n_in; (void)out_size; (void)ws_size;

  // 1+2) per-batch: transpose/split + norms + MFMA correlation (T aliases C1/C2,
  //      dead before convs start)
  for (int b = 0; b < 8; ++b) {
    k_prep<<<dim3(16, 36, 2), 256, 0, stream>>>(fA, fB, b, TAhi, TAlo, TBhi, TBlo, part);
    k_invnorm<<<dim3(9, 2), 256, 0, stream>>>(part, invn, b);
    k_corr_mfma<<<dim3(576), 256, 0, stream>>>(TAhi, TAlo, TBhi, TBlo, invn, b,
                                               pooled + (size_t)b * S4);
  }

  // 3) mutual matching #1 (in place)
  k_rowmax<<<dim3(8 * 576), 64, 0, stream>>>(pooled, amax1);
  k_colmax<<<dim3(8, 9), 256, 0, stream>>>(pooled, bmax1);
  k_mm_apply<<<dim3(10368), 256, 0, stream>>>(pooled, amax1, bmax1, pooled);

  // 4) neighbourhood consensus: 3x conv4d + relu, per batch
  for (int b = 0; b < 8; ++b) {
    k_conv4d<1, 10><<<dim3(576), 576, 0, stream>>>(pooled + (size_t)b * S4, w1, b1, C1);
    k_conv4d<10, 10><<<dim3(576), 576, 0, stream>>>(C1, w2, b2, C2);
    k_conv4d<10, 1><<<dim3(576), 576, 0, stream>>>(C2, w3, b3, C3 + (size_t)b * S4);
  }

  // 5) mutual matching #2 -> final output
  k_rowmax<<<dim3(8 * 576), 64, 0, stream>>>(C3, amax2);
  k_colmax<<<dim3(8, 9), 256, 0, stream>>>(C3, bmax2);
  k_mm_apply<<<dim3(10368), 256, 0, stream>>>(C3, amax2, bmax2, out);
}